// Round 7
// baseline (556.551 us; speedup 1.0000x reference)
//
#include <hip/hip_runtime.h>

// ---------------------------------------------------------------------------
// GAT_L3: 3x (GATConv -> BatchNorm -> ReLU), N=50000, E=800000 (+N self-loops).
// Round 7: gemm rebuilt as wave-per-node with W cached in VGPRs (r5/r6 tiled
// gemm was grid-starved: 391 blocks, 8% occupancy, latency-serialized chunks;
// all layers ~equal time despite different FLOPs). Lane=feature, W column
// loaded once per wave, x row via wave-uniform s_load, K-loop = pure FMA,
// no LDS/barriers. Layer3 (OUTF=32): K split across 32-lane halves.
// BN+ReLU applied by an in-place float4 pass between layers.
// ---------------------------------------------------------------------------

__device__ __forceinline__ float lrelu(float x) { return x > 0.f ? x : 0.2f * x; }
__device__ __forceinline__ unsigned short f2bf(float x) {
    unsigned u = __float_as_uint(x);
    return (unsigned short)((u + 0x7FFFu + ((u >> 16) & 1u)) >> 16);
}
__device__ __forceinline__ float bf2f(unsigned short v) {
    return __uint_as_float(((unsigned)v) << 16);
}

// ---------------------------------------------------------------------------
// Wave-per-node GEMM + attention epilogue.
// OUTF==64: lane j = feature; per-lane W regs = K. H=2 heads reduce in the
//   two 32-lane halves (butterfly m=16..1), lanes 0/32 write es/ed.
// OUTF==32: lane j = lane&31, K split by half-wave (kh = lane>>5), folded
//   with shfl_xor(32); H=1.
// ---------------------------------------------------------------------------
template <int K, int OUTF, int H, int MINW>
__global__ __launch_bounds__(256, MINW) void gemm_wave_k(
    const float* __restrict__ in, const float* __restrict__ W,
    const float* __restrict__ a_src, const float* __restrict__ a_dst,
    unsigned short* __restrict__ hb, float* __restrict__ es,
    float* __restrict__ ed, int N, int waveCount)
{
    constexpr int KR = (OUTF == 32) ? K / 2 : K;   // W regs per lane
    const int lane = threadIdx.x & 63;
    const int wid = blockIdx.x * 4 + (threadIdx.x >> 6);
    const int j = (OUTF == 64) ? lane : (lane & 31);
    const int kh = (OUTF == 32) ? (lane >> 5) : 0;

    float wreg[KR];
#pragma unroll
    for (int k = 0; k < KR; ++k)
        wreg[k] = W[(size_t)(k + kh * KR) * OUTF + j];

    const float asj = a_src[j];
    const float adj = a_dst[j];

    for (int node = wid; node < N; node += waveCount) {
        const int un = __builtin_amdgcn_readfirstlane(node);
        const float* row = in + (size_t)un * K + kh * KR;
        float a0 = 0.f, a1 = 0.f, a2 = 0.f, a3 = 0.f;
#pragma unroll
        for (int k = 0; k < KR; k += 4) {
            a0 = fmaf(row[k + 0], wreg[k + 0], a0);
            a1 = fmaf(row[k + 1], wreg[k + 1], a1);
            a2 = fmaf(row[k + 2], wreg[k + 2], a2);
            a3 = fmaf(row[k + 3], wreg[k + 3], a3);
        }
        float acc = (a0 + a1) + (a2 + a3);
        if constexpr (OUTF == 32) acc += __shfl_xor(acc, 32, 64);

        float p = acc * asj, q = acc * adj;
#pragma unroll
        for (int m = 16; m; m >>= 1) {
            p += __shfl_xor(p, m, 64);
            q += __shfl_xor(q, m, 64);
        }
        if constexpr (OUTF == 64) {
            hb[(size_t)un * OUTF + j] = f2bf(acc);
            if (lane == 0)            { es[un * H + 0] = p; ed[un * H + 0] = q; }
            if (H == 2 && lane == 32) { es[un * H + 1] = p; ed[un * H + 1] = q; }
        } else {
            if (lane < 32) hb[(size_t)un * OUTF + j] = f2bf(acc);
            if (lane == 0) { es[un] = p; ed[un] = q; }
        }
    }
}

// In-place BN-apply + ReLU (float4; feature pattern exact since 4 | F).
template <int F>
__global__ __launch_bounds__(256) void norm_relu_k(
    float* __restrict__ x, const float* __restrict__ sc,
    const float* __restrict__ sh, int total4)
{
    int i = blockIdx.x * 256 + threadIdx.x;
    if (i >= total4) return;
    float4 v = ((float4*)x)[i];
    int f = (i * 4) & (F - 1);
    v.x = fmaxf(v.x * sc[f + 0] + sh[f + 0], 0.f);
    v.y = fmaxf(v.y * sc[f + 1] + sh[f + 1], 0.f);
    v.z = fmaxf(v.z * sc[f + 2] + sh[f + 2], 0.f);
    v.w = fmaxf(v.w * sc[f + 3] + sh[f + 3], 0.f);
    ((float4*)x)[i] = v;
}

// ---------------------------------------------------------------------------
// CSR build: degree histogram -> two-level exclusive scan -> scatter.
// ---------------------------------------------------------------------------
__global__ __launch_bounds__(256) void deg_k(
    const int* __restrict__ ei, int* __restrict__ deg, int E, int N)
{
    int e = blockIdx.x * 256 + threadIdx.x;
    int Et = E + N;
    if (e >= Et) return;
    int d = (e < E) ? ei[E + e] : e - E;
    atomicAdd(&deg[d], 1);
}

__global__ __launch_bounds__(256) void scan1_k(
    const int* __restrict__ deg, int* __restrict__ rowtmp,
    int* __restrict__ bsum, int N)
{
    __shared__ int ls[256];
    int i = blockIdx.x * 256 + threadIdx.x;
    int v = (i < N) ? deg[i] : 0;
    int x = v;
    ls[threadIdx.x] = x;
    __syncthreads();
#pragma unroll
    for (int ofs = 1; ofs < 256; ofs <<= 1) {
        int y = (threadIdx.x >= ofs) ? ls[threadIdx.x - ofs] : 0;
        __syncthreads();
        x += y;
        ls[threadIdx.x] = x;
        __syncthreads();
    }
    if (i < N) rowtmp[i] = x - v;
    if (threadIdx.x == 255) bsum[blockIdx.x] = x;
}

__global__ __launch_bounds__(256) void scan2_k(
    const int* __restrict__ bsum, int* __restrict__ boff, int nb)
{
    __shared__ int ls[256];
    int i = threadIdx.x;
    int v = (i < nb) ? bsum[i] : 0;
    int x = v;
    ls[i] = x;
    __syncthreads();
#pragma unroll
    for (int ofs = 1; ofs < 256; ofs <<= 1) {
        int y = (i >= ofs) ? ls[i - ofs] : 0;
        __syncthreads();
        x += y;
        ls[i] = x;
        __syncthreads();
    }
    if (i < nb) boff[i] = x - v;
}

__global__ __launch_bounds__(256) void scan3_k(
    const int* __restrict__ rowtmp, const int* __restrict__ boff,
    int* __restrict__ rowptr, int N, int Et)
{
    int i = blockIdx.x * 256 + threadIdx.x;
    if (i < N) rowptr[i] = rowtmp[i] + boff[blockIdx.x];
    if (i == 0) rowptr[N] = Et;
}

__global__ __launch_bounds__(256) void scatter_k(
    const int* __restrict__ ei, const int* __restrict__ rowptr,
    int* __restrict__ cur, int* __restrict__ col, int E, int N)
{
    int e = blockIdx.x * 256 + threadIdx.x;
    int Et = E + N;
    if (e >= Et) return;
    int s, d;
    if (e < E) { s = ei[e]; d = ei[E + e]; } else { s = e - E; d = s; }
    int pos = atomicAdd(&cur[d], 1);
    col[rowptr[d] + pos] = s;
}

// ---------------------------------------------------------------------------
// Node softmax, no max pass (logits O(4): exp safe; equals max-subtracted
// softmax). Output per-edge slots:
//   H==2: uint2 {src, bf16(a0) | bf16(a1)<<16}    H==1: float2 {src_bits, a}
// ---------------------------------------------------------------------------
template <int H>
__global__ __launch_bounds__(256) void node_softmax_k(
    const int* __restrict__ rowptr, const int* __restrict__ col,
    const float* __restrict__ es, const float* __restrict__ ed,
    uint2* __restrict__ pkh, float2* __restrict__ pk2, int N)
{
    constexpr int F = H * 32;
    int t = blockIdx.x * 256 + threadIdx.x;
    int node = t / F;
    int lane = t - node * F;
    if (node >= N) return;
    int base = rowptr[node];
    int deg = rowptr[node + 1] - base;

    float ed0 = ed[node * H + 0];
    float ed1 = (H == 2) ? ed[node * H + 1] : 0.f;
    const float2* es2 = (const float2*)es;

    bool have = lane < deg;
    int sc_ = 0;
    float e0c = 0.f, e1c = 0.f;
    if (have) {
        sc_ = col[base + lane];
        if (H == 2) {
            float2 v = es2[sc_];
            e0c = __expf(lrelu(v.x + ed0));
            e1c = __expf(lrelu(v.y + ed1));
        } else {
            e0c = __expf(lrelu(es[sc_] + ed0));
        }
    }
    float s0 = e0c, s1 = e1c;
    for (int e = lane + F; e < deg; e += F) {
        int s = col[base + e];
        if (H == 2) {
            float2 v = es2[s];
            s0 += __expf(lrelu(v.x + ed0));
            s1 += __expf(lrelu(v.y + ed1));
        } else {
            s0 += __expf(lrelu(es[s] + ed0));
        }
    }
#pragma unroll
    for (int m = F / 2; m; m >>= 1) {
        s0 += __shfl_xor(s0, m, F);
        if (H == 2) s1 += __shfl_xor(s1, m, F);
    }
    float rd0 = 1.f / (s0 + 1e-16f);
    float rd1 = (H == 2) ? 1.f / (s1 + 1e-16f) : 0.f;

    if (have) {
        if (H == 2)
            pkh[base + lane] = make_uint2((unsigned)sc_,
                (unsigned)f2bf(e0c * rd0) | ((unsigned)f2bf(e1c * rd1) << 16));
        else
            pk2[base + lane] = make_float2(__int_as_float(sc_), e0c * rd0);
    }
    for (int e = lane + F; e < deg; e += F) {
        int s = col[base + e];
        if (H == 2) {
            float2 v = es2[s];
            pkh[base + e] = make_uint2((unsigned)s,
                (unsigned)f2bf(__expf(lrelu(v.x + ed0)) * rd0)
              | ((unsigned)f2bf(__expf(lrelu(v.y + ed1)) * rd1) << 16));
        } else {
            pk2[base + e] = make_float2(__int_as_float(s),
                                        __expf(lrelu(es[s] + ed0)) * rd0);
        }
    }
}

// ---------------------------------------------------------------------------
// Gather (bf16 h): lane owns feature pair (2l, 2l+1). H==2: 32 lanes/node;
// H==1: 16 lanes/node. Unroll 8 -> 16 loads in flight per round trip.
// ---------------------------------------------------------------------------
template <int H>
__global__ __launch_bounds__(256) void node_gather_k(
    const int* __restrict__ rowptr, const uint2* __restrict__ pkh,
    const float2* __restrict__ pk2, const unsigned short* __restrict__ hb,
    float* __restrict__ out, int N)
{
    constexpr int F = H * 32;
    constexpr int LPN = F / 2;             // lanes per node
    int t = blockIdx.x * 256 + threadIdx.x;
    int node = t / LPN;
    int lane = t - node * LPN;
    if (node >= N) return;
    int base = rowptr[node];
    int deg = rowptr[node + 1] - base;

    const uint* h2 = (const uint*)hb;      // one uint = 2 bf16 features
    float acc0 = 0.f, acc1 = 0.f;
    int e = 0;
    if (H == 2) {
        bool hi = lane >= 16;
        const uint2* p = pkh + base;
        for (; e + 8 <= deg; e += 8) {
            uint v[8];
            float a[8];
#pragma unroll
            for (int u = 0; u < 8; ++u) {
                uint2 q = p[e + u];
                v[u] = h2[(size_t)q.x * LPN + lane];
                a[u] = bf2f((unsigned short)(hi ? (q.y >> 16) : (q.y & 0xFFFFu)));
            }
#pragma unroll
            for (int u = 0; u < 8; ++u) {
                acc0 += a[u] * bf2f((unsigned short)v[u]);
                acc1 += a[u] * bf2f((unsigned short)(v[u] >> 16));
            }
        }
        for (; e < deg; ++e) {
            uint2 q = p[e];
            uint v = h2[(size_t)q.x * LPN + lane];
            float a = bf2f((unsigned short)(hi ? (q.y >> 16) : (q.y & 0xFFFFu)));
            acc0 += a * bf2f((unsigned short)v);
            acc1 += a * bf2f((unsigned short)(v >> 16));
        }
    } else {
        const float2* p = pk2 + base;
        for (; e + 8 <= deg; e += 8) {
            uint v[8];
            float a[8];
#pragma unroll
            for (int u = 0; u < 8; ++u) {
                float2 q = p[e + u];
                v[u] = h2[(size_t)__float_as_int(q.x) * LPN + lane];
                a[u] = q.y;
            }
#pragma unroll
            for (int u = 0; u < 8; ++u) {
                acc0 += a[u] * bf2f((unsigned short)v[u]);
                acc1 += a[u] * bf2f((unsigned short)(v[u] >> 16));
            }
        }
        for (; e < deg; ++e) {
            float2 q = p[e];
            uint v = h2[(size_t)__float_as_int(q.x) * LPN + lane];
            acc0 += q.y * bf2f((unsigned short)v);
            acc1 += q.y * bf2f((unsigned short)(v >> 16));
        }
    }
    ((float2*)out)[(size_t)node * LPN + lane] = make_float2(acc0, acc1);
}

// ---------------------------------------------------------------------------
// BN: atomic-free two-stage stats, then scale/shift finalize.
// ---------------------------------------------------------------------------
template <int F>
__global__ __launch_bounds__(256) void bn_stats_k(
    const float* __restrict__ x, float* __restrict__ psum,
    float* __restrict__ psumsq, int N)
{
    constexpr int RG = 256 / F;
    int f = threadIdx.x & (F - 1);
    int r = threadIdx.x / F;
    float s = 0.f, s2 = 0.f;
    for (int n = blockIdx.x * RG + r; n < N; n += gridDim.x * RG) {
        float v = x[(size_t)n * F + f];
        s += v;
        s2 += v * v;
    }
    __shared__ float ls[256], ls2[256];
    ls[threadIdx.x] = s;
    ls2[threadIdx.x] = s2;
    __syncthreads();
    if (threadIdx.x < F) {
#pragma unroll
        for (int g = 1; g < RG; ++g) { s += ls[g * F + f]; s2 += ls2[g * F + f]; }
        psum[blockIdx.x * F + f] = s;
        psumsq[blockIdx.x * F + f] = s2;
    }
}

__global__ void bn_final_k(const float* __restrict__ psum,
                           const float* __restrict__ psumsq,
                           const float* __restrict__ gamma,
                           const float* __restrict__ beta,
                           float* __restrict__ scale, float* __restrict__ shift,
                           int N, int F, int NB)
{
    int f = threadIdx.x;
    if (f >= F) return;
    float s = 0.f, s2 = 0.f;
    for (int b = 0; b < NB; ++b) { s += psum[b * F + f]; s2 += psumsq[b * F + f]; }
    float inv = 1.f / (float)N;
    float mu = s * inv;
    float var = s2 * inv - mu * mu;
    var = fmaxf(var, 0.f);
    float rs = rsqrtf(var + 1e-5f);
    float sc = rs * gamma[f];
    scale[f] = sc;
    shift[f] = beta[f] - mu * sc;
}

__global__ __launch_bounds__(256) void out_final_k(
    const float* __restrict__ x, const float* __restrict__ scale,
    const float* __restrict__ shift, float* __restrict__ out, int total)
{
    int i = blockIdx.x * 256 + threadIdx.x;
    if (i >= total) return;
    int f = i & 31;
    out[i] = fmaxf(x[i] * scale[f] + shift[f], 0.f);
}

// ---------------------------------------------------------------------------

extern "C" void kernel_launch(void* const* d_in, const int* in_sizes, int n_in,
                              void* d_out, int out_size, void* d_ws,
                              size_t ws_size, hipStream_t stream)
{
    const float* x   = (const float*)d_in[0];
    const float* W1  = (const float*)d_in[1];
    const float* as1 = (const float*)d_in[2];
    const float* ad1 = (const float*)d_in[3];
    const float* g1  = (const float*)d_in[5];
    const float* be1 = (const float*)d_in[6];
    const float* W2  = (const float*)d_in[7];
    const float* as2 = (const float*)d_in[8];
    const float* ad2 = (const float*)d_in[9];
    const float* g2  = (const float*)d_in[11];
    const float* be2 = (const float*)d_in[12];
    const float* W3  = (const float*)d_in[13];
    const float* as3 = (const float*)d_in[14];
    const float* ad3 = (const float*)d_in[15];
    const float* g3  = (const float*)d_in[17];
    const float* be3 = (const float*)d_in[18];
    const int*   ei  = (const int*)d_in[19];

    const int N  = in_sizes[0] / 128;   // 50000
    const int E  = in_sizes[19] / 2;    // 800000
    const int Et = E + N;
    const int nb = (N + 255) / 256;
    const int NBN = 128;                // bn_stats blocks

    // Workspace layout (4-byte words), packed slots 8B-aligned.
    float* ws = (float*)d_ws;
    size_t off = 0;
    unsigned short* Hb = (unsigned short*)(ws + off); off += (size_t)N * 32; // bf16 [N,64]
    float* AGG = ws + off;  off += (size_t)N * 64;
    float* ES  = ws + off;  off += (size_t)N * 2;
    float* ED  = ws + off;  off += (size_t)N * 2;
    float* SC  = ws + off;  off += 64;
    float* SH  = ws + off;  off += 64;
    float* PS  = ws + off;  off += (size_t)NBN * 64;
    float* PS2 = ws + off;  off += (size_t)NBN * 64;
    int* deg    = (int*)(ws + off);  off += N;        // reused as cursor
    int* rowtmp = (int*)(ws + off);  off += N;
    int* bsum   = (int*)(ws + off);  off += 256;
    int* boff   = (int*)(ws + off);  off += 256;
    int* rowptr = (int*)(ws + off);  off += (size_t)N + 1;
    int* col    = (int*)(ws + off);  off += (size_t)Et;
    off = (off + 3) & ~(size_t)3;                      // 16B align
    uint2*  PKH = (uint2*)(ws + off);                  // Et 8B slots (H=2)
    float2* PK2 = (float2*)PKH;                        // reused for layer 3

    const int gemmBlocks   = 768;                      // 3072 waves, all resident
    const int gemmWaves    = gemmBlocks * 4;
    const int n64Blocks    = (int)(((size_t)N * 64 + 255) / 256);
    const int n32Blocks    = (int)(((size_t)N * 32 + 255) / 256);
    const int g64Blocks    = (int)(((size_t)N * 32 + 255) / 256);  // LPN=32
    const int g32Blocks    = (int)(((size_t)N * 16 + 255) / 256);  // LPN=16
    const int edgeBlocks   = (Et + 255) / 256;
    const int nrBlocks64   = (N * 16 + 255) / 256;     // float4 units

    // ---------------- CSR build (once per call) ----------------
    hipMemsetAsync(deg, 0, (size_t)N * sizeof(int), stream);
    deg_k<<<edgeBlocks, 256, 0, stream>>>(ei, deg, E, N);
    scan1_k<<<nb, 256, 0, stream>>>(deg, rowtmp, bsum, N);
    scan2_k<<<1, 256, 0, stream>>>(bsum, boff, nb);
    scan3_k<<<nb, 256, 0, stream>>>(rowtmp, boff, rowptr, N, Et);
    hipMemsetAsync(deg, 0, (size_t)N * sizeof(int), stream);
    scatter_k<<<edgeBlocks, 256, 0, stream>>>(ei, rowptr, deg, col, E, N);

    // ---------------- Layer 1: 128 -> [2 x 32] ----------------
    gemm_wave_k<128, 64, 2, 3><<<gemmBlocks, 256, 0, stream>>>(
        x, W1, as1, ad1, Hb, ES, ED, N, gemmWaves);
    node_softmax_k<2><<<n64Blocks, 256, 0, stream>>>(rowptr, col, ES, ED, PKH, PK2, N);
    node_gather_k<2><<<g64Blocks, 256, 0, stream>>>(rowptr, PKH, PK2, Hb, AGG, N);
    bn_stats_k<64><<<NBN, 256, 0, stream>>>(AGG, PS, PS2, N);
    bn_final_k<<<1, 64, 0, stream>>>(PS, PS2, g1, be1, SC, SH, N, 64, NBN);

    // ---------------- Layer 2: 64 -> [2 x 32] ----------------
    norm_relu_k<64><<<nrBlocks64, 256, 0, stream>>>(AGG, SC, SH, N * 16);
    gemm_wave_k<64, 64, 2, 5><<<gemmBlocks, 256, 0, stream>>>(
        AGG, W2, as2, ad2, Hb, ES, ED, N, gemmWaves);
    node_softmax_k<2><<<n64Blocks, 256, 0, stream>>>(rowptr, col, ES, ED, PKH, PK2, N);
    node_gather_k<2><<<g64Blocks, 256, 0, stream>>>(rowptr, PKH, PK2, Hb, AGG, N);
    bn_stats_k<64><<<NBN, 256, 0, stream>>>(AGG, PS, PS2, N);
    bn_final_k<<<1, 64, 0, stream>>>(PS, PS2, g2, be2, SC, SH, N, 64, NBN);

    // ---------------- Layer 3: 64 -> [1 x 32] ----------------
    norm_relu_k<64><<<nrBlocks64, 256, 0, stream>>>(AGG, SC, SH, N * 16);
    gemm_wave_k<64, 32, 1, 8><<<gemmBlocks, 256, 0, stream>>>(
        AGG, W3, as3, ad3, Hb, ES, ED, N, gemmWaves);
    node_softmax_k<1><<<n32Blocks, 256, 0, stream>>>(rowptr, col, ES, ED, PKH, PK2, N);
    node_gather_k<1><<<g32Blocks, 256, 0, stream>>>(rowptr, PKH, PK2, Hb, AGG, N);
    bn_stats_k<32><<<NBN, 256, 0, stream>>>(AGG, PS, PS2, N);
    bn_final_k<<<1, 32, 0, stream>>>(PS, PS2, g3, be3, SC, SH, N, 32, NBN);
    out_final_k<<<n32Blocks, 256, 0, stream>>>(AGG, SC, SH, (float*)d_out, N * 32);
}